// Round 10
// baseline (181.387 us; speedup 1.0000x reference)
//
#include <hip/hip_runtime.h>
#include <hip/hip_bf16.h>
#include <stdint.h>

using bf16_t = __hip_bfloat16;
typedef __bf16 bf16x8 __attribute__((ext_vector_type(8)));
typedef float f32x4 __attribute__((ext_vector_type(4)));

// ---------------------------------------------------------------- helpers
__device__ __forceinline__ void async_lds16(const void* g, void* l) {
  // global -> LDS direct copy, 16B/lane. LDS dest = wave-uniform base +
  // lane*16 (m104/m108); global source is per-lane (m173).
  __builtin_amdgcn_global_load_lds(
      (const __attribute__((address_space(1))) void*)g,
      (__attribute__((address_space(3))) void*)l, 16, 0, 0);
}

__device__ __forceinline__ unsigned short f2bf_u16(float f) {
  __hip_bfloat16 h = __float2bfloat16(f);
  return __builtin_bit_cast(unsigned short, h);
}

__device__ __forceinline__ float bf2f(unsigned short u) {
  __hip_bfloat16 h = __builtin_bit_cast(__hip_bfloat16, u);
  return __bfloat162float(h);
}

// ------------------------------------------------ fused converts (x and W)
__global__ __launch_bounds__(256) void convert_all_kernel(
    const float* __restrict__ x, bf16_t* __restrict__ xb,
    const float* __restrict__ Wq, const float* __restrict__ Wk,
    const float* __restrict__ Wv, bf16_t* __restrict__ wt) {
  __shared__ bf16_t tile[32][33];
  const int bid = blockIdx.x;
  if (bid < 8192) {
    size_t i = ((size_t)bid * 256 + threadIdx.x) * 4;
    float4 v = *(const float4*)(x + i);
    ushort4 o;
    o.x = f2bf_u16(v.x);
    o.y = f2bf_u16(v.y);
    o.z = f2bf_u16(v.z);
    o.w = f2bf_u16(v.w);
    *(ushort4*)(xb + i) = o;
    return;
  }
  const int w = bid - 8192;            // 0..3071
  const int z = w >> 10;               // which W
  const int bxy = w & 1023;
  const float* W = (z == 0) ? Wq : (z == 1) ? Wk : Wv;
  bf16_t* WT = wt + (size_t)z * 1024 * 1024;
  const int tx = threadIdx.x & 31;
  const int ty = threadIdx.x >> 5;     // 0..7
  const int bx = bxy & 31;
  const int by = bxy >> 5;
  const int k0 = by * 32, n0 = bx * 32;
#pragma unroll
  for (int j = 0; j < 32; j += 8)
    tile[ty + j][tx] = __float2bfloat16(W[(size_t)(k0 + ty + j) * 1024 + n0 + tx]);
  __syncthreads();
#pragma unroll
  for (int j = 0; j < 32; j += 8)
    WT[(size_t)(n0 + ty + j) * 1024 + k0 + tx] = tile[tx][ty + j];
}

// ------------------------------------------------------- projection GEMM
// R7-proven best (71.5 us, 0 conflicts, MfmaUtil 29): 128x256 tile, BK=32,
// 8 waves (2M x 4N), 3 LDS buffers (72 KB), counted-vmcnt pipeline. T2
// swizzle both sides. OUT_MODE 3 = QKV routing.
template <int OUT_MODE>
__global__ __launch_bounds__(512, 2) void gemm_pipe_kernel(
    const bf16_t* __restrict__ A, const bf16_t* __restrict__ BT,
    void* __restrict__ Cv, void* __restrict__ Cv2, void* __restrict__ Cv3,
    int M, int N, int K, int lda, int ldb) {
  int bx = blockIdx.x, by = blockIdx.y;
  {  // bijective XCD swizzle (grid multiple of 8)
    const int gx = gridDim.x;
    const int nwg = gx * gridDim.y;
    const int id = by * gx + bx;
    const int cpx = nwg >> 3;
    const int swz = (id & 7) * cpx + (id >> 3);
    by = swz / gx;
    bx = swz % gx;
  }
  const int m0 = by * 128;
  const int n0 = bx * 256;
  const int nkt = K >> 5;

  __shared__ bf16_t lsA[3 * 4096];  // 24 KB
  __shared__ bf16_t lsB[3 * 8192];  // 48 KB

  const int tid = threadIdx.x;
  const int wid = tid >> 6;
  const int lane = tid & 63;
  const int wm = wid >> 2;  // 0..1
  const int wn = wid & 3;   // 0..3

  const int sr = tid >> 2;
  const int ss = tid & 3;
  const int sswz = ss ^ ((sr >> 1) & 3);  // T2 involution
  const bf16_t* gA = A + (size_t)(m0 + sr) * lda + sswz * 8;
  const bf16_t* gB0 = BT + (size_t)(n0 + sr) * ldb + sswz * 8;
  const bf16_t* gB1 = BT + (size_t)(n0 + 128 + sr) * ldb + sswz * 8;

  const int kslot = (lane >> 4) ^ ((lane >> 1) & 3);
  const int abase = (wm * 64 + (lane & 15)) * 32 + kslot * 8;
  const int bbase = (wn * 64 + (lane & 15)) * 32 + kslot * 8;

  f32x4 acc[4][4];
  const f32x4 zero = {0.f, 0.f, 0.f, 0.f};
#pragma unroll
  for (int m = 0; m < 4; ++m)
#pragma unroll
    for (int n = 0; n < 4; ++n) acc[m][n] = zero;

  async_lds16(gA, lsA + wid * 512);
  async_lds16(gB0, lsB + wid * 512);
  async_lds16(gB1, lsB + 4096 + wid * 512);
  if (nkt > 1) {
    async_lds16(gA + 32, lsA + 4096 + wid * 512);
    async_lds16(gB0 + 32, lsB + 8192 + wid * 512);
    async_lds16(gB1 + 32, lsB + 8192 + 4096 + wid * 512);
    asm volatile("s_waitcnt vmcnt(3)" ::: "memory");
  } else {
    asm volatile("s_waitcnt vmcnt(0)" ::: "memory");
  }
  __builtin_amdgcn_s_barrier();

  int cb = 0;
  for (int t = 0; t < nkt; ++t) {
    const bf16_t* bufA = lsA + cb * 4096;
    const bf16_t* bufB = lsB + cb * 8192;
    int sb = cb + 2;
    if (sb >= 3) sb -= 3;

    bf16x8 af[4], bfr[4];
#pragma unroll
    for (int mf = 0; mf < 4; ++mf)
      af[mf] = *(const bf16x8*)(bufA + abase + mf * 512);
    bfr[0] = *(const bf16x8*)(bufB + bbase);
    bfr[1] = *(const bf16x8*)(bufB + bbase + 512);
    if (t + 2 < nkt) {
      async_lds16(gA + (t + 2) * 32, lsA + sb * 4096 + wid * 512);
      async_lds16(gB0 + (t + 2) * 32, lsB + sb * 8192 + wid * 512);
    }
    __builtin_amdgcn_s_barrier();
    __builtin_amdgcn_s_setprio(1);
#pragma unroll
    for (int mf = 0; mf < 4; ++mf)
#pragma unroll
      for (int nf = 0; nf < 2; ++nf)
        acc[mf][nf] = __builtin_amdgcn_mfma_f32_16x16x32_bf16(
            af[mf], bfr[nf], acc[mf][nf], 0, 0, 0);
    __builtin_amdgcn_s_setprio(0);
    __builtin_amdgcn_s_barrier();

    bfr[2] = *(const bf16x8*)(bufB + bbase + 1024);
    bfr[3] = *(const bf16x8*)(bufB + bbase + 1536);
    if (t + 2 < nkt)
      async_lds16(gB1 + (t + 2) * 32, lsB + sb * 8192 + 4096 + wid * 512);
    if (t + 2 < nkt) {
      asm volatile("s_waitcnt vmcnt(3)" ::: "memory");
    } else if (t + 2 == nkt) {
      asm volatile("s_waitcnt vmcnt(0)" ::: "memory");
    }
    __builtin_amdgcn_s_barrier();
    __builtin_amdgcn_s_setprio(1);
#pragma unroll
    for (int mf = 0; mf < 4; ++mf)
#pragma unroll
      for (int nf = 2; nf < 4; ++nf)
        acc[mf][nf] = __builtin_amdgcn_mfma_f32_16x16x32_bf16(
            af[mf], bfr[nf], acc[mf][nf], 0, 0, 0);
    __builtin_amdgcn_s_setprio(0);
    __builtin_amdgcn_s_barrier();

    cb = cb + 1;
    if (cb >= 3) cb -= 3;
  }

  // epilogue: C/D frag layout col=lane&15, row=(lane>>4)*4+j (m89/m91)
  const int erow = wm * 64 + (lane >> 4) * 4;
  const int ecol = wn * 64 + (lane & 15);
  if (n0 < 2048) {
    bf16_t* C = (bf16_t*)((n0 < 1024) ? Cv : Cv2);
    const int cb0 = n0 & 1023;
#pragma unroll
    for (int m = 0; m < 4; ++m)
#pragma unroll
      for (int n = 0; n < 4; ++n)
#pragma unroll
        for (int j = 0; j < 4; ++j) {
          int r = m0 + erow + m * 16 + j;
          int c = cb0 + ecol + n * 16;
          C[(size_t)r * 1024 + c] = __float2bfloat16(acc[m][n][j]);
        }
  } else {
    // V^T batched: row r in [0,8192) -> b=r>>11, t=r&2047 ; VT[b][d][t]
    bf16_t* C = (bf16_t*)Cv3;
    const int d0 = n0 - 2048;
#pragma unroll
    for (int m = 0; m < 4; ++m)
#pragma unroll
      for (int n = 0; n < 4; ++n)
#pragma unroll
        for (int j = 0; j < 4; ++j) {
          int r = m0 + erow + m * 16 + j;
          int d = d0 + ecol + n * 16;
          int b = r >> 11, tt = r & 2047;
          C[((size_t)b * 1024 + d) * 2048 + tt] = __float2bfloat16(acc[m][n][j]);
        }
  }
}

// ---------------------------------------------------------------- QK^T GEMM
// (R7 proven) 128x128 tile, 8 waves (2M x 4N), 64x32/wave, 3 LDS buffers
// (48 KB), counted vmcnt(2). CAUSAL_SKIP: skip bx > by. bf16 out pitch ldc.
__global__ __launch_bounds__(512, 2) void gemm_qkt_kernel(
    const bf16_t* __restrict__ A, const bf16_t* __restrict__ BT,
    bf16_t* __restrict__ Cv, int K, int lda, int ldb, int ldc,
    long long aBatch, long long bBatch, long long cBatch) {
  const int bx = blockIdx.x, by = blockIdx.y;
  if (bx > by) return;  // tile fully above causal diagonal
  const bf16_t* Ab = A + (size_t)blockIdx.z * aBatch;
  const bf16_t* Bb = BT + (size_t)blockIdx.z * bBatch;

  __shared__ bf16_t lsA[3 * 4096];  // 24 KB
  __shared__ bf16_t lsB[3 * 4096];  // 24 KB

  const int tid = threadIdx.x;
  const int wid = tid >> 6;
  const int lane = tid & 63;
  const int wm = wid >> 2;  // 0..1
  const int wn = wid & 3;   // 0..3

  const int sr = tid >> 2;                       // row 0..127
  const int sswz = (tid & 3) ^ ((sr >> 1) & 3);  // T2 involution
  const int n0 = bx * 128;
  const int m0 = by * 128;
  const bf16_t* gB = Bb + (size_t)(n0 + sr) * ldb + sswz * 8;
  const bf16_t* gA = Ab + (size_t)(m0 + sr) * lda + sswz * 8;

  const int kslot = (lane >> 4) ^ ((lane >> 1) & 3);
  const int aRd = (wm * 64 + (lane & 15)) * 32 + kslot * 8;
  const int bRd = (wn * 32 + (lane & 15)) * 32 + kslot * 8;

  const int nkt = K >> 5;

  f32x4 acc[4][2];
  const f32x4 zero = {0.f, 0.f, 0.f, 0.f};
#pragma unroll
  for (int m = 0; m < 4; ++m)
#pragma unroll
    for (int n = 0; n < 2; ++n) acc[m][n] = zero;

  // prologue: stage tiles 0,1; confirm tile 0
  async_lds16(gA, lsA + wid * 512);
  async_lds16(gB, lsB + wid * 512);
  async_lds16(gA + 32, lsA + 4096 + wid * 512);
  async_lds16(gB + 32, lsB + 4096 + wid * 512);
  asm volatile("s_waitcnt vmcnt(2)" ::: "memory");
  __builtin_amdgcn_s_barrier();

  int cb = 0;
  for (int t = 0; t < nkt; ++t) {
    const bf16_t* bufA = lsA + cb * 4096;
    const bf16_t* bufB = lsB + cb * 4096;
    int sb = cb + 2;
    if (sb >= 3) sb -= 3;

    bf16x8 af[4], bfr[2];
#pragma unroll
    for (int mf = 0; mf < 4; ++mf)
      af[mf] = *(const bf16x8*)(bufA + aRd + mf * 512);
    bfr[0] = *(const bf16x8*)(bufB + bRd);
    bfr[1] = *(const bf16x8*)(bufB + bRd + 512);
    if (t + 2 < nkt) {
      async_lds16(gA + (t + 2) * 32, lsA + sb * 4096 + wid * 512);
      async_lds16(gB + (t + 2) * 32, lsB + sb * 4096 + wid * 512);
      asm volatile("s_waitcnt vmcnt(2)" ::: "memory");  // tile t+1 resident
    } else if (t + 2 == nkt) {
      asm volatile("s_waitcnt vmcnt(0)" ::: "memory");  // drain last stage
    }
    __builtin_amdgcn_s_barrier();
    __builtin_amdgcn_s_setprio(1);
#pragma unroll
    for (int mf = 0; mf < 4; ++mf)
#pragma unroll
      for (int nf = 0; nf < 2; ++nf)
        acc[mf][nf] = __builtin_amdgcn_mfma_f32_16x16x32_bf16(
            af[mf], bfr[nf], acc[mf][nf], 0, 0, 0);
    __builtin_amdgcn_s_setprio(0);
    __builtin_amdgcn_s_barrier();

    cb = cb + 1;
    if (cb >= 3) cb -= 3;
  }

  // epilogue: bf16 row-major
  const int erow = wm * 64 + (lane >> 4) * 4;
  const int ecol = wn * 32 + (lane & 15);
  bf16_t* C = Cv + (size_t)blockIdx.z * cBatch;
#pragma unroll
  for (int m = 0; m < 4; ++m)
#pragma unroll
    for (int n = 0; n < 2; ++n)
#pragma unroll
      for (int j = 0; j < 4; ++j) {
        int r = m0 + erow + m * 16 + j;
        int c = n0 + ecol + n * 16;
        C[(size_t)r * ldc + c] = __float2bfloat16(acc[m][n][j]);
      }
}

// ---------------------------------------------------------------- PV GEMM
// O = P * VT^T with 64-row M-panels paired for uniform load AND 2 blocks/CU:
// grid (8,16,z): bx = d_v 128-col tile; by pairs panels (by, 31-by) of 64
// rows -> klimit steps (2by+2)+(64-2by) = 66 uniform. 8 waves (2M x 4N),
// wave tile 32x32, acc[2][2]. 3 LDS buffers: A 3x4KB (12KB), B 3x8KB (24KB)
// = 36 KB -> 2+ blocks/CU. A region (4 KB) is written by waves 0-3 AND
// duplicated by waves 4-7 (same source bytes -> benign race) so every wave
// issues exactly 2 gload_lds per step and per-wave vmcnt counting stays
// uniform: stage t+2, boundary vmcnt(2) retires tile t+1. T2 swizzle.
__global__ __launch_bounds__(512, 2) void gemm_pv_kernel(
    const bf16_t* __restrict__ P, const bf16_t* __restrict__ VT,
    float* __restrict__ O, long long aBatch, long long bBatch,
    long long cBatch) {
  const int bx = blockIdx.x;   // 0..7  d_v col tile
  const int by = blockIdx.y;   // 0..15 panel pair
  const bf16_t* Pb = P + (size_t)blockIdx.z * aBatch;
  const bf16_t* Vb = VT + (size_t)blockIdx.z * bBatch;
  float* Ob = O + (size_t)blockIdx.z * cBatch;

  __shared__ bf16_t lsA[3 * 2048];  // 12 KB: [buf][64 rows][32 k]
  __shared__ bf16_t lsB[3 * 4096];  // 24 KB: [buf][128 rows][32 k]

  const int tid = threadIdx.x;
  const int wid = tid >> 6;
  const int lane = tid & 63;
  const int wm = wid >> 2;  // 0..1
  const int wn = wid & 3;   // 0..3

  const int n0 = bx * 128;
  // B staging: 128 rows x 64B, all 8 waves
  const int srB = tid >> 2;
  const int swzB = (tid & 3) ^ ((srB >> 1) & 3);
  const bf16_t* gB = Vb + (size_t)(n0 + srB) * 2048 + swzB * 8;
  // A staging: 64 rows x 64B; waves 4-7 duplicate waves 0-3
  const int tA = tid & 255;
  const int srA = tA >> 2;
  const int swzA = (tA & 3) ^ ((srA >> 1) & 3);

  const int kslot = (lane >> 4) ^ ((lane >> 1) & 3);
  const int aRd = (wm * 32 + (lane & 15)) * 32 + kslot * 8;
  const int bRd = (wn * 32 + (lane & 15)) * 32 + kslot * 8;

#pragma unroll 1
  for (int job = 0; job < 2; ++job) {
    const int pidx = job ? (31 - by) : by;
    const int m0 = pidx * 64;
    int nkt = 2 * pidx + 2;
    nkt = nkt < 64 ? nkt : 64;  // always >= 2
    const bf16_t* gA = Pb + (size_t)(m0 + srA) * 4096 + swzA * 8;

    f32x4 acc[2][2];
    const f32x4 zero = {0.f, 0.f, 0.f, 0.f};
#pragma unroll
    for (int m = 0; m < 2; ++m)
#pragma unroll
      for (int n = 0; n < 2; ++n) acc[m][n] = zero;

    // prologue: stage tiles 0,1; confirm tile 0
    async_lds16(gA, lsA + (wid & 3) * 512);
    async_lds16(gB, lsB + wid * 512);
    async_lds16(gA + 32, lsA + 2048 + (wid & 3) * 512);
    async_lds16(gB + 32, lsB + 4096 + wid * 512);
    asm volatile("s_waitcnt vmcnt(2)" ::: "memory");
    __builtin_amdgcn_s_barrier();

    int cb = 0;
    for (int t = 0; t < nkt; ++t) {
      const bf16_t* bufA = lsA + cb * 2048;
      const bf16_t* bufB = lsB + cb * 4096;
      int sb = cb + 2;
      if (sb >= 3) sb -= 3;

      bf16x8 af[2], bfr[2];
      af[0] = *(const bf16x8*)(bufA + aRd);
      af[1] = *(const bf16x8*)(bufA + aRd + 512);
      bfr[0] = *(const bf16x8*)(bufB + bRd);
      bfr[1] = *(const bf16x8*)(bufB + bRd + 512);
      if (t + 2 < nkt) {
        async_lds16(gA + (t + 2) * 32, lsA + sb * 2048 + (wid & 3) * 512);
        async_lds16(gB + (t + 2) * 32, lsB + sb * 4096 + wid * 512);
        asm volatile("s_waitcnt vmcnt(2)" ::: "memory");  // tile t+1 resident
      } else if (t + 2 == nkt) {
        asm volatile("s_waitcnt vmcnt(0)" ::: "memory");  // drain last stage
      }
      __builtin_amdgcn_s_barrier();
      __builtin_amdgcn_s_setprio(1);
#pragma unroll
      for (int mf = 0; mf < 2; ++mf)
#pragma unroll
        for (int nf = 0; nf < 2; ++nf)
          acc[mf][nf] = __builtin_amdgcn_mfma_f32_16x16x32_bf16(
              af[mf], bfr[nf], acc[mf][nf], 0, 0, 0);
      __builtin_amdgcn_s_setprio(0);
      __builtin_amdgcn_s_barrier();

      cb = cb + 1;
      if (cb >= 3) cb -= 3;
    }

    // epilogue: C/D frag layout col=lane&15, row=(lane>>4)*4+j
    const int erow = wm * 32 + (lane >> 4) * 4;
    const int ecol = wn * 32 + (lane & 15);
#pragma unroll
    for (int m = 0; m < 2; ++m)
#pragma unroll
      for (int n = 0; n < 2; ++n)
#pragma unroll
        for (int j = 0; j < 4; ++j) {
          int r = m0 + erow + m * 16 + j;
          int c = n0 + ecol + n * 16;
          Ob[(size_t)r * 1024 + c] = acc[m][n][j];
        }
    // all waves passed the loop's final barrier before job-1 staging; the
    // final vmcnt(0) drained all loads -> LDS reuse across jobs is safe.
  }
}

// ---------------------------------------------------------------- softmax
// One wave per (b,t) row; S bf16 (row pitch 4096 bf16). Causal softmax of
// scale*S; P bf16 in place (row fully register-staged first). Causal trim:
// only 256-col quads it <= t>>8 touched.
__global__ __launch_bounds__(256) void softmax_causal_kernel(bf16_t* __restrict__ Sb) {
  const int lane = threadIdx.x & 63;
  const int rg = blockIdx.x * 4 + (threadIdx.x >> 6);
  const int b = rg >> 11;
  const int t = rg & 2047;
  bf16_t* srow = Sb + (size_t)b * 8388608 + (size_t)t * 4096;
  const int qmax = t >> 8;  // quads 0..qmax are live

  float v[8][4];
#pragma unroll
  for (int it = 0; it < 8; ++it) {
    if (it <= qmax) {
      ushort4 u = *(const ushort4*)(srow + (it * 64 + lane) * 4);
      v[it][0] = bf2f(u.x);
      v[it][1] = bf2f(u.y);
      v[it][2] = bf2f(u.z);
      v[it][3] = bf2f(u.w);
    } else {
      v[it][0] = v[it][1] = v[it][2] = v[it][3] = 0.f;
    }
  }

  float mx = -3.0e38f;
#pragma unroll
  for (int it = 0; it < 8; ++it) {
    int s0 = (it * 64 + lane) * 4;
    if (s0 + 0 <= t) mx = fmaxf(mx, v[it][0]);
    if (s0 + 1 <= t) mx = fmaxf(mx, v[it][1]);
    if (s0 + 2 <= t) mx = fmaxf(mx, v[it][2]);
    if (s0 + 3 <= t) mx = fmaxf(mx, v[it][3]);
  }
#pragma unroll
  for (int off = 32; off > 0; off >>= 1) mx = fmaxf(mx, __shfl_xor(mx, off, 64));

  const float kMul = 0.03125f * 1.4426950408889634f;  // scale * log2(e)
  float p[8][4];
  float sum = 0.f;
#pragma unroll
  for (int it = 0; it < 8; ++it) {
    int s0 = (it * 64 + lane) * 4;
    float e0 = (s0 + 0 <= t) ? exp2f((v[it][0] - mx) * kMul) : 0.f;
    float e1 = (s0 + 1 <= t) ? exp2f((v[it][1] - mx) * kMul) : 0.f;
    float e2 = (s0 + 2 <= t) ? exp2f((v[it][2] - mx) * kMul) : 0.f;
    float e3 = (s0 + 3 <= t) ? exp2f((v[it][3] - mx) * kMul) : 0.f;
    p[it][0] = e0; p[it][1] = e1; p[it][2] = e2; p[it][3] = e3;
    sum += (e0 + e1) + (e2 + e3);
  }
#pragma unroll
  for (int off = 32; off > 0; off >>= 1) sum += __shfl_xor(sum, off, 64);
  const float inv = 1.f / sum;

#pragma unroll
  for (int it = 0; it < 8; ++it) {
    if (it <= qmax) {
      ushort4 o;
      o.x = f2bf_u16(p[it][0] * inv);
      o.y = f2bf_u16(p[it][1] * inv);
      o.z = f2bf_u16(p[it][2] * inv);
      o.w = f2bf_u16(p[it][3] * inv);
      *(ushort4*)(srow + (it * 64 + lane) * 4) = o;
    }
  }
}

// ---------------------------------------------------------------- launch
extern "C" void kernel_launch(void* const* d_in, const int* in_sizes, int n_in,
                              void* d_out, int out_size, void* d_ws, size_t ws_size,
                              hipStream_t stream) {
  (void)in_sizes; (void)n_in; (void)out_size;
  const float* x = (const float*)d_in[0];
  const float* Wq = (const float*)d_in[1];
  const float* Wk = (const float*)d_in[2];
  const float* Wv = (const float*)d_in[3];
  float* out = (float*)d_out;

  char* ws = (char*)d_ws;
  // batched layout (requires ~118 MiB):
  //   [0, 67.1M)        S_all (bf16, [4][2048] rows, pitch 4096 bf16);
  //                     xb (bf16 8192x1024) aliases the front (dead by then)
  //   [67.1M, 73.4M)    WT (bf16 [3072][1024], Wq^T|Wk^T|Wv^T stacked)
  //   [73.4M, 90.2M)    Q  (bf16 8192x1024)
  //   [90.2M, 107.0M)   K  (bf16 8192x1024)
  //   [107.0M, 123.7M)  VT (bf16 [4][1024][2048])
  const size_t NEED = 123731968;
  const bool batched = ws_size >= NEED;

  bf16_t* xb = (bf16_t*)ws;
  bf16_t* Sb;
  bf16_t *WT, *Qb, *Kb, *VT;
  if (batched) {
    Sb = (bf16_t*)ws;
    WT = (bf16_t*)(ws + 67108864);
    Qb = (bf16_t*)(ws + 73400320);
    Kb = (bf16_t*)(ws + 90177536);
    VT = (bf16_t*)(ws + 106954752);
  } else {
    Sb = (bf16_t*)ws;
    WT = (bf16_t*)(ws + 16777216);
    Qb = (bf16_t*)(ws + 16777216 + 6291456);
    Kb = Qb + 8388608;
    VT = Kb + 8388608;
  }

  // 1. fused conversions (x -> bf16 ; W -> bf16 transposed stacked)
  convert_all_kernel<<<11264, 256, 0, stream>>>(x, xb, Wq, Wk, Wv, WT);

  // 2. merged QKV projection (R7-best kernel): 768 blocks, XCD-swizzled
  gemm_pipe_kernel<3><<<dim3(12, 64, 1), 512, 0, stream>>>(
      xb, WT, Qb, Kb, VT, 8192, 3072, 1024, 1024, 1024);

  const int nbat = batched ? 4 : 1;
  for (int pass = 0; pass < (batched ? 1 : 4); ++pass) {
    const size_t qoff = (size_t)pass * 2048 * 1024;
    const bf16_t* Qp = Qb + qoff;
    const bf16_t* Kp = Kb + qoff;
    const bf16_t* Vp = VT + qoff;
    float* op = out + qoff;
    // 3. S = Q K^T (causal skip), bf16 out, pitch 4096
    gemm_qkt_kernel<<<dim3(16, 16, nbat), 512, 0, stream>>>(
        Qp, Kp, Sb, 1024, 1024, 1024, 4096,
        batched ? 2097152LL : 0, batched ? 2097152LL : 0,
        batched ? 8388608LL : 0);
    // 4. softmax -> P (bf16 in place, causal-trimmed)
    softmax_causal_kernel<<<batched ? 2048 : 512, 256, 0, stream>>>(Sb);
    // 5. O = P V: 64-row paired panels, 512 blocks (2/CU), uniform 66 steps
    gemm_pv_kernel<<<dim3(8, 16, nbat), 512, 0, stream>>>(
        Sb, Vp, op,
        batched ? 8388608LL : 0, batched ? 2097152LL : 0,
        batched ? 2097152LL : 0);
  }
}

// Round 11
// 174.599 us; speedup vs baseline: 1.0389x; 1.0389x over previous
//
#include <hip/hip_runtime.h>
#include <hip/hip_bf16.h>
#include <stdint.h>

using bf16_t = __hip_bfloat16;
typedef __bf16 bf16x8 __attribute__((ext_vector_type(8)));
typedef float f32x4 __attribute__((ext_vector_type(4)));

// ---------------------------------------------------------------- helpers
__device__ __forceinline__ void async_lds16(const void* g, void* l) {
  // global -> LDS direct copy, 16B/lane. LDS dest = wave-uniform base +
  // lane*16 (m104/m108); global source is per-lane (m173).
  __builtin_amdgcn_global_load_lds(
      (const __attribute__((address_space(1))) void*)g,
      (__attribute__((address_space(3))) void*)l, 16, 0, 0);
}

__device__ __forceinline__ unsigned short f2bf_u16(float f) {
  __hip_bfloat16 h = __float2bfloat16(f);
  return __builtin_bit_cast(unsigned short, h);
}

__device__ __forceinline__ float bf2f(unsigned short u) {
  __hip_bfloat16 h = __builtin_bit_cast(__hip_bfloat16, u);
  return __bfloat162float(h);
}

// ------------------------------------------------ fused converts (x and W)
__global__ __launch_bounds__(256) void convert_all_kernel(
    const float* __restrict__ x, bf16_t* __restrict__ xb,
    const float* __restrict__ Wq, const float* __restrict__ Wk,
    const float* __restrict__ Wv, bf16_t* __restrict__ wt) {
  __shared__ bf16_t tile[32][33];
  const int bid = blockIdx.x;
  if (bid < 8192) {
    size_t i = ((size_t)bid * 256 + threadIdx.x) * 4;
    float4 v = *(const float4*)(x + i);
    ushort4 o;
    o.x = f2bf_u16(v.x);
    o.y = f2bf_u16(v.y);
    o.z = f2bf_u16(v.z);
    o.w = f2bf_u16(v.w);
    *(ushort4*)(xb + i) = o;
    return;
  }
  const int w = bid - 8192;            // 0..3071
  const int z = w >> 10;               // which W
  const int bxy = w & 1023;
  const float* W = (z == 0) ? Wq : (z == 1) ? Wk : Wv;
  bf16_t* WT = wt + (size_t)z * 1024 * 1024;
  const int tx = threadIdx.x & 31;
  const int ty = threadIdx.x >> 5;     // 0..7
  const int bx = bxy & 31;
  const int by = bxy >> 5;
  const int k0 = by * 32, n0 = bx * 32;
#pragma unroll
  for (int j = 0; j < 32; j += 8)
    tile[ty + j][tx] = __float2bfloat16(W[(size_t)(k0 + ty + j) * 1024 + n0 + tx]);
  __syncthreads();
#pragma unroll
  for (int j = 0; j < 32; j += 8)
    WT[(size_t)(n0 + ty + j) * 1024 + k0 + tx] = tile[tx][ty + j];
}

// ------------------------------------------------------- projection GEMM
// Measured-best projection (71.5 us, 0 conflicts, MfmaUtil ~29): 128x256
// tile, BK=32, 8 waves (2M x 4N), 3 LDS buffers (72 KB), counted-vmcnt
// pipeline (stage t+2 while computing t; boundary vmcnt(3) retires t+1).
// T2 swizzle both sides. OUT_MODE 3 = QKV routing.
template <int OUT_MODE>
__global__ __launch_bounds__(512, 2) void gemm_pipe_kernel(
    const bf16_t* __restrict__ A, const bf16_t* __restrict__ BT,
    void* __restrict__ Cv, void* __restrict__ Cv2, void* __restrict__ Cv3,
    int M, int N, int K, int lda, int ldb) {
  int bx = blockIdx.x, by = blockIdx.y;
  {  // bijective XCD swizzle (grid multiple of 8)
    const int gx = gridDim.x;
    const int nwg = gx * gridDim.y;
    const int id = by * gx + bx;
    const int cpx = nwg >> 3;
    const int swz = (id & 7) * cpx + (id >> 3);
    by = swz / gx;
    bx = swz % gx;
  }
  const int m0 = by * 128;
  const int n0 = bx * 256;
  const int nkt = K >> 5;

  __shared__ bf16_t lsA[3 * 4096];  // 24 KB
  __shared__ bf16_t lsB[3 * 8192];  // 48 KB

  const int tid = threadIdx.x;
  const int wid = tid >> 6;
  const int lane = tid & 63;
  const int wm = wid >> 2;  // 0..1
  const int wn = wid & 3;   // 0..3

  const int sr = tid >> 2;
  const int ss = tid & 3;
  const int sswz = ss ^ ((sr >> 1) & 3);  // T2 involution
  const bf16_t* gA = A + (size_t)(m0 + sr) * lda + sswz * 8;
  const bf16_t* gB0 = BT + (size_t)(n0 + sr) * ldb + sswz * 8;
  const bf16_t* gB1 = BT + (size_t)(n0 + 128 + sr) * ldb + sswz * 8;

  const int kslot = (lane >> 4) ^ ((lane >> 1) & 3);
  const int abase = (wm * 64 + (lane & 15)) * 32 + kslot * 8;
  const int bbase = (wn * 64 + (lane & 15)) * 32 + kslot * 8;

  f32x4 acc[4][4];
  const f32x4 zero = {0.f, 0.f, 0.f, 0.f};
#pragma unroll
  for (int m = 0; m < 4; ++m)
#pragma unroll
    for (int n = 0; n < 4; ++n) acc[m][n] = zero;

  async_lds16(gA, lsA + wid * 512);
  async_lds16(gB0, lsB + wid * 512);
  async_lds16(gB1, lsB + 4096 + wid * 512);
  if (nkt > 1) {
    async_lds16(gA + 32, lsA + 4096 + wid * 512);
    async_lds16(gB0 + 32, lsB + 8192 + wid * 512);
    async_lds16(gB1 + 32, lsB + 8192 + 4096 + wid * 512);
    asm volatile("s_waitcnt vmcnt(3)" ::: "memory");
  } else {
    asm volatile("s_waitcnt vmcnt(0)" ::: "memory");
  }
  __builtin_amdgcn_s_barrier();

  int cb = 0;
  for (int t = 0; t < nkt; ++t) {
    const bf16_t* bufA = lsA + cb * 4096;
    const bf16_t* bufB = lsB + cb * 8192;
    int sb = cb + 2;
    if (sb >= 3) sb -= 3;

    bf16x8 af[4], bfr[4];
#pragma unroll
    for (int mf = 0; mf < 4; ++mf)
      af[mf] = *(const bf16x8*)(bufA + abase + mf * 512);
    bfr[0] = *(const bf16x8*)(bufB + bbase);
    bfr[1] = *(const bf16x8*)(bufB + bbase + 512);
    if (t + 2 < nkt) {
      async_lds16(gA + (t + 2) * 32, lsA + sb * 4096 + wid * 512);
      async_lds16(gB0 + (t + 2) * 32, lsB + sb * 8192 + wid * 512);
    }
    __builtin_amdgcn_s_barrier();
    __builtin_amdgcn_s_setprio(1);
#pragma unroll
    for (int mf = 0; mf < 4; ++mf)
#pragma unroll
      for (int nf = 0; nf < 2; ++nf)
        acc[mf][nf] = __builtin_amdgcn_mfma_f32_16x16x32_bf16(
            af[mf], bfr[nf], acc[mf][nf], 0, 0, 0);
    __builtin_amdgcn_s_setprio(0);
    __builtin_amdgcn_s_barrier();

    bfr[2] = *(const bf16x8*)(bufB + bbase + 1024);
    bfr[3] = *(const bf16x8*)(bufB + bbase + 1536);
    if (t + 2 < nkt)
      async_lds16(gB1 + (t + 2) * 32, lsB + sb * 8192 + 4096 + wid * 512);
    if (t + 2 < nkt) {
      asm volatile("s_waitcnt vmcnt(3)" ::: "memory");
    } else if (t + 2 == nkt) {
      asm volatile("s_waitcnt vmcnt(0)" ::: "memory");
    }
    __builtin_amdgcn_s_barrier();
    __builtin_amdgcn_s_setprio(1);
#pragma unroll
    for (int mf = 0; mf < 4; ++mf)
#pragma unroll
      for (int nf = 2; nf < 4; ++nf)
        acc[mf][nf] = __builtin_amdgcn_mfma_f32_16x16x32_bf16(
            af[mf], bfr[nf], acc[mf][nf], 0, 0, 0);
    __builtin_amdgcn_s_setprio(0);
    __builtin_amdgcn_s_barrier();

    cb = cb + 1;
    if (cb >= 3) cb -= 3;
  }

  // epilogue: C/D frag layout col=lane&15, row=(lane>>4)*4+j (m89/m91)
  const int erow = wm * 64 + (lane >> 4) * 4;
  const int ecol = wn * 64 + (lane & 15);
  if (n0 < 2048) {
    bf16_t* C = (bf16_t*)((n0 < 1024) ? Cv : Cv2);
    const int cb0 = n0 & 1023;
#pragma unroll
    for (int m = 0; m < 4; ++m)
#pragma unroll
      for (int n = 0; n < 4; ++n)
#pragma unroll
        for (int j = 0; j < 4; ++j) {
          int r = m0 + erow + m * 16 + j;
          int c = cb0 + ecol + n * 16;
          C[(size_t)r * 1024 + c] = __float2bfloat16(acc[m][n][j]);
        }
  } else {
    // V^T batched: row r in [0,8192) -> b=r>>11, t=r&2047 ; VT[b][d][t]
    bf16_t* C = (bf16_t*)Cv3;
    const int d0 = n0 - 2048;
#pragma unroll
    for (int m = 0; m < 4; ++m)
#pragma unroll
      for (int n = 0; n < 4; ++n)
#pragma unroll
        for (int j = 0; j < 4; ++j) {
          int r = m0 + erow + m * 16 + j;
          int d = d0 + ecol + n * 16;
          int b = r >> 11, tt = r & 2047;
          C[((size_t)b * 1024 + d) * 2048 + tt] = __float2bfloat16(acc[m][n][j]);
        }
  }
}

// ---------------------------------------------------------------- GEMM 128x128
// Attention GEMMs (R7, measured best): 128x128 tile, 8 waves (2M x 4N),
// 64x32/wave. 3 LDS buffers (48 KB), counted-vmcnt: stage tile t+2 while
// computing t; boundary vmcnt(2) retires tile t+1. T2 swizzle (0 conflicts).
// PAIRED (PV): block (bx, by in [0,8)) does M-panels by and 15-by -> every
// block exactly 68 K-steps (uniform). CAUSAL_SKIP (QK^T): skip bx > by.
// OUT_MODE: 2 = f32 row-major (pitch ldc); 5 = bf16 row-major (pitch ldc).
template <int OUT_MODE, bool CAUSAL_SKIP, bool PAIRED>
__global__ __launch_bounds__(512, 2) void gemm128_kernel(
    const bf16_t* __restrict__ A, const bf16_t* __restrict__ BT,
    void* __restrict__ Cv, int K, int lda, int ldb, int ldc,
    long long aBatch, long long bBatch, long long cBatch) {
  const int bx = blockIdx.x, by = blockIdx.y;
  if (CAUSAL_SKIP && bx > by) return;  // tile fully above causal diagonal
  const bf16_t* Ab = A + (size_t)blockIdx.z * aBatch;
  const bf16_t* Bb = BT + (size_t)blockIdx.z * bBatch;

  __shared__ bf16_t lsA[3 * 4096];  // 24 KB, buffer stride 4096 elems
  __shared__ bf16_t lsB[3 * 4096];  // 24 KB

  const int tid = threadIdx.x;
  const int wid = tid >> 6;
  const int lane = tid & 63;
  const int wm = wid >> 2;  // 0..1
  const int wn = wid & 3;   // 0..3

  const int sr = tid >> 2;                       // row 0..127
  const int sswz = (tid & 3) ^ ((sr >> 1) & 3);  // T2 involution
  const int n0 = bx * 128;
  const bf16_t* gB = Bb + (size_t)(n0 + sr) * ldb + sswz * 8;

  const int kslot = (lane >> 4) ^ ((lane >> 1) & 3);
  const int aRd = (wm * 64 + (lane & 15)) * 32 + kslot * 8;
  const int bRd = (wn * 32 + (lane & 15)) * 32 + kslot * 8;

  const int njobs = PAIRED ? 2 : 1;
  for (int job = 0; job < njobs; ++job) {
    const int byE = (PAIRED && job) ? (15 - by) : by;
    const int m0 = byE * 128;
    int nkt = K >> 5;
    if (PAIRED) {
      int lim = (m0 + 128) >> 5;  // causal k-limit for PV
      nkt = nkt < lim ? nkt : lim;
    }
    const bf16_t* gA = Ab + (size_t)(m0 + sr) * lda + sswz * 8;

    f32x4 acc[4][2];
    const f32x4 zero = {0.f, 0.f, 0.f, 0.f};
#pragma unroll
    for (int m = 0; m < 4; ++m)
#pragma unroll
      for (int n = 0; n < 2; ++n) acc[m][n] = zero;

    // prologue: stage tiles 0,1; confirm tile 0
    async_lds16(gA, lsA + wid * 512);
    async_lds16(gB, lsB + wid * 512);
    if (nkt > 1) {
      async_lds16(gA + 32, lsA + 4096 + wid * 512);
      async_lds16(gB + 32, lsB + 4096 + wid * 512);
      asm volatile("s_waitcnt vmcnt(2)" ::: "memory");
    } else {
      asm volatile("s_waitcnt vmcnt(0)" ::: "memory");
    }
    __builtin_amdgcn_s_barrier();

    int cb = 0;
    for (int t = 0; t < nkt; ++t) {
      const bf16_t* bufA = lsA + cb * 4096;
      const bf16_t* bufB = lsB + cb * 4096;
      int sb = cb + 2;
      if (sb >= 3) sb -= 3;

      bf16x8 af[4], bfr[2];
#pragma unroll
      for (int mf = 0; mf < 4; ++mf)
        af[mf] = *(const bf16x8*)(bufA + aRd + mf * 512);
      bfr[0] = *(const bf16x8*)(bufB + bRd);
      bfr[1] = *(const bf16x8*)(bufB + bRd + 512);
      if (t + 2 < nkt) {
        async_lds16(gA + (t + 2) * 32, lsA + sb * 4096 + wid * 512);
        async_lds16(gB + (t + 2) * 32, lsB + sb * 4096 + wid * 512);
        asm volatile("s_waitcnt vmcnt(2)" ::: "memory");  // tile t+1 resident
      } else if (t + 2 == nkt) {
        asm volatile("s_waitcnt vmcnt(0)" ::: "memory");  // drain last stage
      }
      __builtin_amdgcn_s_barrier();
      __builtin_amdgcn_s_setprio(1);
#pragma unroll
      for (int mf = 0; mf < 4; ++mf)
#pragma unroll
        for (int nf = 0; nf < 2; ++nf)
          acc[mf][nf] = __builtin_amdgcn_mfma_f32_16x16x32_bf16(
              af[mf], bfr[nf], acc[mf][nf], 0, 0, 0);
      __builtin_amdgcn_s_setprio(0);
      __builtin_amdgcn_s_barrier();

      cb = cb + 1;
      if (cb >= 3) cb -= 3;
    }

    // epilogue: C/D frag layout col=lane&15, row=(lane>>4)*4+j
    const int erow = wm * 64 + (lane >> 4) * 4;
    const int ecol = wn * 32 + (lane & 15);
    if (OUT_MODE == 2) {
      float* C = (float*)Cv + (size_t)blockIdx.z * cBatch;
#pragma unroll
      for (int m = 0; m < 4; ++m)
#pragma unroll
        for (int n = 0; n < 2; ++n)
#pragma unroll
          for (int j = 0; j < 4; ++j) {
            int r = m0 + erow + m * 16 + j;
            int c = n0 + ecol + n * 16;
            C[(size_t)r * ldc + c] = acc[m][n][j];
          }
    } else {  // OUT_MODE == 5: bf16 row-major
      bf16_t* C = (bf16_t*)Cv + (size_t)blockIdx.z * cBatch;
#pragma unroll
      for (int m = 0; m < 4; ++m)
#pragma unroll
        for (int n = 0; n < 2; ++n)
#pragma unroll
          for (int j = 0; j < 4; ++j) {
            int r = m0 + erow + m * 16 + j;
            int c = n0 + ecol + n * 16;
            C[(size_t)r * ldc + c] = __float2bfloat16(acc[m][n][j]);
          }
    }
  }
}

// ---------------------------------------------------------------- softmax
// One wave per (b,t) row; S bf16 (row pitch 4096 bf16). Causal softmax of
// scale*S; P bf16 in place (row fully register-staged first). Causal trim:
// only 256-col quads it <= t>>8 touched (PV klimit window covers exactly
// those; trim zeroes the masked tail inside the window).
__global__ __launch_bounds__(256) void softmax_causal_kernel(bf16_t* __restrict__ Sb) {
  const int lane = threadIdx.x & 63;
  const int rg = blockIdx.x * 4 + (threadIdx.x >> 6);
  const int b = rg >> 11;
  const int t = rg & 2047;
  bf16_t* srow = Sb + (size_t)b * 8388608 + (size_t)t * 4096;
  const int qmax = t >> 8;  // quads 0..qmax are live

  float v[8][4];
#pragma unroll
  for (int it = 0; it < 8; ++it) {
    if (it <= qmax) {
      ushort4 u = *(const ushort4*)(srow + (it * 64 + lane) * 4);
      v[it][0] = bf2f(u.x);
      v[it][1] = bf2f(u.y);
      v[it][2] = bf2f(u.z);
      v[it][3] = bf2f(u.w);
    } else {
      v[it][0] = v[it][1] = v[it][2] = v[it][3] = 0.f;
    }
  }

  float mx = -3.0e38f;
#pragma unroll
  for (int it = 0; it < 8; ++it) {
    int s0 = (it * 64 + lane) * 4;
    if (s0 + 0 <= t) mx = fmaxf(mx, v[it][0]);
    if (s0 + 1 <= t) mx = fmaxf(mx, v[it][1]);
    if (s0 + 2 <= t) mx = fmaxf(mx, v[it][2]);
    if (s0 + 3 <= t) mx = fmaxf(mx, v[it][3]);
  }
#pragma unroll
  for (int off = 32; off > 0; off >>= 1) mx = fmaxf(mx, __shfl_xor(mx, off, 64));

  const float kMul = 0.03125f * 1.4426950408889634f;  // scale * log2(e)
  float p[8][4];
  float sum = 0.f;
#pragma unroll
  for (int it = 0; it < 8; ++it) {
    int s0 = (it * 64 + lane) * 4;
    float e0 = (s0 + 0 <= t) ? exp2f((v[it][0] - mx) * kMul) : 0.f;
    float e1 = (s0 + 1 <= t) ? exp2f((v[it][1] - mx) * kMul) : 0.f;
    float e2 = (s0 + 2 <= t) ? exp2f((v[it][2] - mx) * kMul) : 0.f;
    float e3 = (s0 + 3 <= t) ? exp2f((v[it][3] - mx) * kMul) : 0.f;
    p[it][0] = e0; p[it][1] = e1; p[it][2] = e2; p[it][3] = e3;
    sum += (e0 + e1) + (e2 + e3);
  }
#pragma unroll
  for (int off = 32; off > 0; off >>= 1) sum += __shfl_xor(sum, off, 64);
  const float inv = 1.f / sum;

#pragma unroll
  for (int it = 0; it < 8; ++it) {
    if (it <= qmax) {
      ushort4 o;
      o.x = f2bf_u16(p[it][0] * inv);
      o.y = f2bf_u16(p[it][1] * inv);
      o.z = f2bf_u16(p[it][2] * inv);
      o.w = f2bf_u16(p[it][3] * inv);
      *(ushort4*)(srow + (it * 64 + lane) * 4) = o;
    }
  }
}

// ---------------------------------------------------------------- launch
extern "C" void kernel_launch(void* const* d_in, const int* in_sizes, int n_in,
                              void* d_out, int out_size, void* d_ws, size_t ws_size,
                              hipStream_t stream) {
  (void)in_sizes; (void)n_in; (void)out_size;
  const float* x = (const float*)d_in[0];
  const float* Wq = (const float*)d_in[1];
  const float* Wk = (const float*)d_in[2];
  const float* Wv = (const float*)d_in[3];
  float* out = (float*)d_out;

  char* ws = (char*)d_ws;
  // batched layout (requires ~118 MiB):
  //   [0, 67.1M)        S_all (bf16, [4][2048] rows, pitch 4096 bf16);
  //                     xb (bf16 8192x1024) aliases the front (dead by then)
  //   [67.1M, 73.4M)    WT (bf16 [3072][1024], Wq^T|Wk^T|Wv^T stacked)
  //   [73.4M, 90.2M)    Q  (bf16 8192x1024)
  //   [90.2M, 107.0M)   K  (bf16 8192x1024)
  //   [107.0M, 123.7M)  VT (bf16 [4][1024][2048])
  const size_t NEED = 123731968;
  const bool batched = ws_size >= NEED;

  bf16_t* xb = (bf16_t*)ws;
  bf16_t* Sb;
  bf16_t *WT, *Qb, *Kb, *VT;
  if (batched) {
    Sb = (bf16_t*)ws;
    WT = (bf16_t*)(ws + 67108864);
    Qb = (bf16_t*)(ws + 73400320);
    Kb = (bf16_t*)(ws + 90177536);
    VT = (bf16_t*)(ws + 106954752);
  } else {
    Sb = (bf16_t*)ws;
    WT = (bf16_t*)(ws + 16777216);
    Qb = (bf16_t*)(ws + 16777216 + 6291456);
    Kb = Qb + 8388608;
    VT = Kb + 8388608;
  }

  // 1. fused conversions (x -> bf16 ; W -> bf16 transposed stacked)
  convert_all_kernel<<<11264, 256, 0, stream>>>(x, xb, Wq, Wk, Wv, WT);

  // 2. merged QKV projection: [8192,3072] = [8192,1024] x [3072,1024]^T
  //    proven 128x256 kernel; 768 blocks, XCD-swizzled (768 % 8 == 0)
  gemm_pipe_kernel<3><<<dim3(12, 64, 1), 512, 0, stream>>>(
      xb, WT, Qb, Kb, VT, 8192, 3072, 1024, 1024, 1024);

  const int nbat = batched ? 4 : 1;
  for (int pass = 0; pass < (batched ? 1 : 4); ++pass) {
    const size_t qoff = (size_t)pass * 2048 * 1024;
    const bf16_t* Qp = Qb + qoff;
    const bf16_t* Kp = Kb + qoff;
    const bf16_t* Vp = VT + qoff;
    float* op = out + qoff;
    // 3. S = Q K^T (causal skip), bf16 out, pitch 4096; 544 active blocks
    gemm128_kernel<5, true, false><<<dim3(16, 16, nbat), 512, 0, stream>>>(
        Qp, Kp, Sb, 1024, 1024, 1024, 4096,
        batched ? 2097152LL : 0, batched ? 2097152LL : 0,
        batched ? 8388608LL : 0);
    // 4. softmax -> P (bf16 in place, causal-trimmed)
    softmax_causal_kernel<<<batched ? 2048 : 512, 256, 0, stream>>>(Sb);
    // 5. O = P V, paired M-panels (by,15-by): 68 K-steps per block uniform
    gemm128_kernel<2, false, true><<<dim3(8, 8, nbat), 512, 0, stream>>>(
        Sb, Vp, op, 2048, 4096, 2048, 1024,
        batched ? 8388608LL : 0, batched ? 2097152LL : 0,
        batched ? 2097152LL : 0);
  }
}